// Round 1
// 803.101 us; speedup vs baseline: 1.3848x; 1.3848x over previous
//
#include <hip/hip_runtime.h>
#include <hip/hip_bf16.h>
#include <math.h>

#define B_ 16
#define L_ 2048
#define H_ 768
#define INNER_ 384
#define MU_MAX_ 10.0f
#define LAM_ 0.1f
#define EDGES_ (2 * L_ - 3)   // 4093

typedef short v8bf __attribute__((ext_vector_type(8)));   // 8 bf16 (4 VGPRs)
typedef float v4f  __attribute__((ext_vector_type(4)));   // MFMA accumulator

static __device__ __forceinline__ float wave_sum(float v) {
    #pragma unroll
    for (int o = 32; o > 0; o >>= 1) v += __shfl_xor(v, o, 64);
    return v;
}

static __device__ __forceinline__ float dot4(const float4& a, const float4& b) {
    return a.x * b.x + a.y * b.y + a.z * b.z + a.w * b.w;
}

static __device__ __forceinline__ void fma4(float4& a, float c, float4 x) {
    a.x = fmaf(c, x.x, a.x); a.y = fmaf(c, x.y, a.y);
    a.z = fmaf(c, x.z, a.z); a.w = fmaf(c, x.w, a.w);
}

// round-to-nearest-even fp32 -> bf16 (matches numpy/JAX casting)
static __device__ __forceinline__ ushort f2bf(float x) {
    unsigned u = __float_as_uint(x);
    u += 0x7fffu + ((u >> 16) & 1u);
    return (ushort)(u >> 16);
}

// ---------------- convert hidden fp32 -> bf16 (8 elems/thread) ----------------
__global__ __launch_bounds__(256) void conv_bf16_kernel(
    const float* __restrict__ in, ushort* __restrict__ out, int n8)
{
    int t = blockIdx.x * 256 + threadIdx.x;
    if (t >= n8) return;
    float4 a = ((const float4*)in)[2 * t];
    float4 b = ((const float4*)in)[2 * t + 1];
    ushort r[8] = { f2bf(a.x), f2bf(a.y), f2bf(a.z), f2bf(a.w),
                    f2bf(b.x), f2bf(b.y), f2bf(b.z), f2bf(b.w) };
    ((v8bf*)out)[t] = *(v8bf*)r;
}

// ---------------- convert + transpose wq (K x N fp32) -> wt (N x K bf16) -------
__global__ __launch_bounds__(256) void conv_wqt_kernel(
    const float* __restrict__ wq, ushort* __restrict__ wt)
{
    __shared__ float tile[64][65];
    int k0 = blockIdx.x * 64, n0 = blockIdx.y * 64;
    int t = threadIdx.x;
    #pragma unroll
    for (int it = 0; it < 16; ++it) {
        int lin = t + it * 256;
        int r = lin >> 6, c = lin & 63;         // r: k, c: n  (coalesced read)
        tile[r][c] = wq[(size_t)(k0 + r) * H_ + n0 + c];
    }
    __syncthreads();
    #pragma unroll
    for (int it = 0; it < 16; ++it) {
        int lin = t + it * 256;
        int r = lin >> 6, c = lin & 63;         // r: n, c: k  (coalesced write)
        wt[(size_t)(n0 + r) * H_ + k0 + c] = f2bf(tile[c][r]);
    }
}

// ---------------- MFMA GEMM: q = A(bf16) @ wt^T + bq ----------------
#define GBM 128
#define GBN 128
#define GBK 64
#define LSTR 72   // padded LDS row stride in bf16 (2-way bank alias = free)

__global__ __launch_bounds__(256) void gemm_q_kernel(
    const ushort* __restrict__ A, const ushort* __restrict__ Wt,
    const float* __restrict__ bias, float* __restrict__ C)
{
    __shared__ ushort As[GBM * LSTR];
    __shared__ ushort Bs[GBN * LSTR];
    const int K = H_, N = H_;
    int m0 = blockIdx.x * GBM;
    int n0 = blockIdx.y * GBN;
    int t = threadIdx.x;
    int lane = t & 63, w = t >> 6;
    int wm = (w & 1) * 64, wn = (w >> 1) * 64;
    int row16 = lane & 15, quad = lane >> 4;

    v4f acc[4][4];
    #pragma unroll
    for (int i = 0; i < 4; ++i)
        #pragma unroll
        for (int j = 0; j < 4; ++j)
            acc[i][j] = (v4f){0.f, 0.f, 0.f, 0.f};

    for (int k0 = 0; k0 < K; k0 += GBK) {
        #pragma unroll
        for (int it = 0; it < 4; ++it) {
            int lin = t + it * 256;           // 0..1023
            int r = lin >> 3;                 // row 0..127
            int s = lin & 7;                  // 16B segment 0..7
            *(v8bf*)&As[r * LSTR + s * 8] =
                *(const v8bf*)(A + (size_t)(m0 + r) * K + k0 + s * 8);
            *(v8bf*)&Bs[r * LSTR + s * 8] =
                *(const v8bf*)(Wt + (size_t)(n0 + r) * K + k0 + s * 8);
        }
        __syncthreads();
        #pragma unroll
        for (int h = 0; h < 2; ++h) {
            v8bf af[4], bf[4];
            #pragma unroll
            for (int i = 0; i < 4; ++i)
                af[i] = *(v8bf*)&As[(wm + i * 16 + row16) * LSTR + h * 32 + quad * 8];
            #pragma unroll
            for (int j = 0; j < 4; ++j)
                bf[j] = *(v8bf*)&Bs[(wn + j * 16 + row16) * LSTR + h * 32 + quad * 8];
            #pragma unroll
            for (int i = 0; i < 4; ++i)
                #pragma unroll
                for (int j = 0; j < 4; ++j)
                    acc[i][j] = __builtin_amdgcn_mfma_f32_16x16x32_bf16(
                        af[i], bf[j], acc[i][j], 0, 0, 0);
        }
        __syncthreads();
    }
    #pragma unroll
    for (int j = 0; j < 4; ++j) {
        int ncol = n0 + wn + j * 16 + row16;
        float bqv = bias[ncol];
        #pragma unroll
        for (int i = 0; i < 4; ++i) {
            int mrow = m0 + wm + i * 16 + quad * 4;
            #pragma unroll
            for (int r = 0; r < 4; ++r)
                C[(size_t)(mrow + r) * N + ncol] = acc[i][j][r] + bqv;
        }
    }
}

// ---------------- mu: one wave per row t, computes m1(t,t+1), m2(t,t+2) -------
// MLP weights preloaded per-lane (INNER=384 -> 6 regs each). dist/cos built
// from ss_i + ss_j - 2*dot (same formula as previous passing kernel).
static __device__ __forceinline__ float mu_mlp2(
    float si, float sj, float dotij,
    const float* w1d, const float* w1c, const float* b1v, const float* w2v,
    float b2v)
{
    float dist = sqrtf(fmaxf(si + sj - 2.f * dotij, 0.f));
    float cosv = dotij / (fmaxf(sqrtf(si), 1e-6f) * fmaxf(sqrtf(sj), 1e-6f));
    float acc = 0.f;
    #pragma unroll
    for (int k = 0; k < 6; ++k) {
        float z = fmaf(dist, w1d[k], fmaf(cosv, w1c[k], b1v[k]));
        float g = 0.5f * z * (1.f + erff(z * 0.70710678118654752f)); // exact gelu
        acc = fmaf(g, w2v[k], acc);
    }
    acc = wave_sum(acc) + b2v;
    float sp = fmaxf(acc, 0.f) + log1pf(expf(-fabsf(acc)));  // stable softplus
    return fminf(sp + 1e-5f, MU_MAX_);
}

__global__ __launch_bounds__(256) void mu_kernel(
    const float* __restrict__ src,
    const float* __restrict__ w1, const float* __restrict__ b1,
    const float* __restrict__ w2, const float* __restrict__ b2,
    float* __restrict__ mu)
{
    int blk = blockIdx.x;
    int sw = (blk & 7) * ((B_ * L_ / 4) / 8) + (blk >> 3);  // XCD-contiguous
    int rg = sw * 4 + (threadIdx.x >> 6);                   // global row
    int lane = threadIdx.x & 63;
    int b = rg >> 11;            // L_ = 2048
    int t = rg & (L_ - 1);
    int o1 = (t + 1 < L_) ? 1 : 0;
    int o2 = (t + 2 < L_) ? 2 : (L_ - 1 - t);
    const float4* r0p = (const float4*)(src + (size_t)rg * H_);
    const float4* r1p = (const float4*)(src + (size_t)(rg + o1) * H_);
    const float4* r2p = (const float4*)(src + (size_t)(rg + o2) * H_);
    float ss0 = 0.f, ss1 = 0.f, ss2 = 0.f, d1 = 0.f, d2 = 0.f;
    #pragma unroll
    for (int ch = 0; ch < 3; ++ch) {
        int off = ch * 64 + lane;
        float4 x = r0p[off], y = r1p[off], z = r2p[off];
        ss0 += dot4(x, x); ss1 += dot4(y, y); ss2 += dot4(z, z);
        d1  += dot4(x, y); d2  += dot4(x, z);
    }
    if (t >= L_ - 1) return;     // last row: no outgoing edges (wave-uniform)
    ss0 = wave_sum(ss0); ss1 = wave_sum(ss1); d1 = wave_sum(d1);

    float w1d[6], w1c[6], b1v[6], w2v[6];
    #pragma unroll
    for (int k = 0; k < 6; ++k) {
        int u = k * 64 + lane;
        w1d[k] = w1[u]; w1c[k] = w1[INNER_ + u]; b1v[k] = b1[u]; w2v[k] = w2[u];
    }
    float b2v = b2[0];

    float m1 = mu_mlp2(ss0, ss1, d1, w1d, w1c, b1v, w2v, b2v);
    if (lane == 0) mu[(size_t)b * EDGES_ + t] = m1;
    if (t < L_ - 2) {
        ss2 = wave_sum(ss2); d2 = wave_sum(d2);
        float m2v = mu_mlp2(ss0, ss2, d2, w1d, w1c, b1v, w2v, b2v);
        if (lane == 0) mu[(size_t)b * EDGES_ + (L_ - 1) + t] = m2v;
    }
}

// ---------------- fused lap-update + smooth as a 7-point linear stencil -------
// out[p] = sum_{d=-3..3} C_d * state[p+d] + coef*(g_-1 q[p-1]+g_0 q[p]+g_1 q[p+1])
// where C is built from the per-row (mu, deg^-1/2) halo. Boundary smooth-clamp
// folds into the g weights (all register indices compile-time).
// Last step additionally fuses residual + LayerNorm (lnout != nullptr).
__global__ __launch_bounds__(256) void update_kernel(
    const float* __restrict__ src, const float* __restrict__ q,
    const float* __restrict__ mu, float* __restrict__ dst,
    const float* __restrict__ hidden, const float* __restrict__ gamma,
    const float* __restrict__ beta, float* __restrict__ lnout,
    float coef)
{
    int blk = blockIdx.x;
    int sw = (blk & 7) * ((B_ * L_ / 4) / 8) + (blk >> 3);  // XCD-contiguous
    int rg = sw * 4 + (threadIdx.x >> 6);
    int lane = threadIdx.x & 63;
    int b = rg >> 11;
    int p = rg & (L_ - 1);
    const float* mp = mu + (size_t)b * EDGES_;

    // mu halo (zero-filled outside valid edge ranges, matching reference deg)
    float m1a[8];
    #pragma unroll
    for (int j = 0; j < 8; ++j) {
        int u = p - 4 + j;
        m1a[j] = (u >= 0 && u < L_ - 1) ? mp[u] : 0.f;
    }
    float m2a[9];
    #pragma unroll
    for (int j = 0; j < 9; ++j) {
        int u = p - 5 + j;
        m2a[j] = (u >= 0 && u < L_ - 2) ? mp[(L_ - 1) + u] : 0.f;
    }
    // inv = deg^-1/2 for rows p-3..p+3 (same add order as previous kernel)
    float invv[7];
    #pragma unroll
    for (int d = 0; d < 7; ++d) {
        int u = p - 3 + d;
        if (u < 0 || u >= L_) { invv[d] = 0.f; }
        else {
            float deg = m1a[d + 1] + m1a[d] + m2a[d + 2] + m2a[d];
            invv[d] = 1.f / sqrtf(fmaxf(deg, 1e-6f));
        }
    }
    // smooth weights with boundary clamp folded in (p=0: left neighbor = self)
    float gwv[3];
    gwv[0] = (p == 0) ? 0.f : LAM_;
    gwv[2] = (p == L_ - 1) ? 0.f : LAM_;
    gwv[1] = 1.f - 2.f * LAM_ + ((p == 0 || p == L_ - 1) ? LAM_ : 0.f);

    float C[7] = {0.f, 0.f, 0.f, 0.f, 0.f, 0.f, 0.f};
    float e[3];
    #pragma unroll
    for (int i = 0; i < 3; ++i) {            // s1 row k = p-1+i
        float g = gwv[i];
        float wm2 = m2a[i + 2] * invv[i + 2] * invv[i];
        float wm1 = m1a[i + 2] * invv[i + 2] * invv[i + 1];
        float wp1 = m1a[i + 3] * invv[i + 2] * invv[i + 3];
        float wp2 = m2a[i + 4] * invv[i + 2] * invv[i + 4];
        float wsum = wm2 + wm1 + wp1 + wp2;
        C[i]     = fmaf(g * coef, wm2, C[i]);
        C[i + 1] = fmaf(g * coef, wm1, C[i + 1]);
        C[i + 2] = fmaf(g, fmaf(-coef, wsum, 1.f), C[i + 2]);
        C[i + 3] = fmaf(g * coef, wp1, C[i + 3]);
        C[i + 4] = fmaf(g * coef, wp2, C[i + 4]);
        e[i] = g * coef;
    }

    int rr[7];
    #pragma unroll
    for (int d = 0; d < 7; ++d) {
        int u = p - 3 + d;
        rr[d] = u < 0 ? 0 : (u >= L_ ? L_ - 1 : u);   // clamped; OOB coef is 0
    }
    int qr[3];
    #pragma unroll
    for (int i = 0; i < 3; ++i) {
        int u = p - 1 + i;
        qr[i] = u < 0 ? 0 : (u >= L_ ? L_ - 1 : u);
    }
    const float* sB = src + (size_t)b * L_ * H_;
    const float* qB = q + (size_t)b * L_ * H_;
    float4 res[3];
    #pragma unroll
    for (int ch = 0; ch < 3; ++ch) {
        int off = ch * 64 + lane;
        float4 acc = {0.f, 0.f, 0.f, 0.f};
        #pragma unroll
        for (int d = 0; d < 7; ++d)
            fma4(acc, C[d], ((const float4*)(sB + (size_t)rr[d] * H_))[off]);
        #pragma unroll
        for (int i = 0; i < 3; ++i)
            fma4(acc, e[i], ((const float4*)(qB + (size_t)qr[i] * H_))[off]);
        ((float4*)(dst + (size_t)rg * H_))[off] = acc;
        res[ch] = acc;
    }

    // ---- fused residual + LayerNorm on the last step ----
    if (lnout) {
        const float4* hB = (const float4*)(hidden + (size_t)rg * H_);
        float sum = 0.f, sq = 0.f;
        float4 r[3];
        #pragma unroll
        for (int ch = 0; ch < 3; ++ch) {
            int off = ch * 64 + lane;
            float4 h = hB[off];
            float4 v;
            v.x = res[ch].x + h.x; v.y = res[ch].y + h.y;
            v.z = res[ch].z + h.z; v.w = res[ch].w + h.w;
            r[ch] = v;
            sum += v.x + v.y + v.z + v.w;
            sq  += v.x * v.x + v.y * v.y + v.z * v.z + v.w * v.w;
        }
        sum = wave_sum(sum); sq = wave_sum(sq);
        float mean = sum * (1.f / H_);
        float var  = sq * (1.f / H_) - mean * mean;
        float rs = 1.f / sqrtf(var + 1e-5f);
        #pragma unroll
        for (int ch = 0; ch < 3; ++ch) {
            int off = ch * 64 + lane;
            float4 g4 = ((const float4*)gamma)[off];
            float4 b4 = ((const float4*)beta)[off];
            float4 o;
            o.x = (r[ch].x - mean) * rs * g4.x + b4.x;
            o.y = (r[ch].y - mean) * rs * g4.y + b4.y;
            o.z = (r[ch].z - mean) * rs * g4.z + b4.z;
            o.w = (r[ch].w - mean) * rs * g4.w + b4.w;
            ((float4*)(lnout + (size_t)rg * H_))[off] = o;
        }
    }
}

// ---------------- energy ----------------
__global__ void zero_energy_kernel(float* __restrict__ e) {
    if (threadIdx.x < B_) e[threadIdx.x] = 0.f;
}

// One block = 64 edges of one batch (4 waves x 16 edges). One atomic per block.
#define EPW 16
__global__ __launch_bounds__(256) void energy_kernel(
    const float* __restrict__ state, const int* __restrict__ ei, const int* __restrict__ ej,
    const float* __restrict__ mu, float* __restrict__ energy, int E)
{
    __shared__ float red[4];
    int wib = threadIdx.x >> 6;
    int lane = threadIdx.x & 63;
    int nchunk = (E + 63) / 64;
    int b = blockIdx.x / nchunk;
    int chunk = blockIdx.x - b * nchunk;
    int e0 = chunk * 64 + wib * EPW;
    const float* base = state + (size_t)b * L_ * H_;
    const float* muB = mu + (size_t)b * E;
    float part = 0.f;
    for (int k = 0; k < EPW; ++k) {
        int e = e0 + k;
        if (e >= E) break;
        int i = ei[e], j = ej[e];
        const float4* ri = (const float4*)(base + (size_t)i * H_);
        const float4* rj = (const float4*)(base + (size_t)j * H_);
        float s = 0.f;
        #pragma unroll
        for (int it = 0; it < 3; ++it) {
            float4 xi = ri[it * 64 + lane], xj = rj[it * 64 + lane];
            float dx = xi.x - xj.x, dy = xi.y - xj.y, dz = xi.z - xj.z, dw = xi.w - xj.w;
            s += dx*dx + dy*dy + dz*dz + dw*dw;
        }
        s = wave_sum(s);
        part += muB[e] * s;
    }
    if (lane == 0) red[wib] = part;
    __syncthreads();
    if (threadIdx.x == 0)
        atomicAdd(energy + b, 0.5f * (red[0] + red[1] + red[2] + red[3]));
}

extern "C" void kernel_launch(void* const* d_in, const int* in_sizes, int n_in,
                              void* d_out, int out_size, void* d_ws, size_t ws_size,
                              hipStream_t stream)
{
    const float* hidden = (const float*)d_in[0];
    // d_in[1] attention_mask: all ones, unused by the reference math
    const float* w1 = (const float*)d_in[2];
    const float* b1 = (const float*)d_in[3];
    const float* w2 = (const float*)d_in[4];
    const float* b2 = (const float*)d_in[5];
    const float* wq = (const float*)d_in[6];
    const float* bq = (const float*)d_in[7];
    const float* gamma = (const float*)d_in[8];
    const float* beta  = (const float*)d_in[9];
    const int* ei = (const int*)d_in[10];
    const int* ej = (const int*)d_in[11];
    int E = in_sizes[10];   // 2L-3 = 4093

    const size_t BLH = (size_t)B_ * L_ * H_;
    float* out = (float*)d_out;
    float* energy = out + BLH;   // outputs concatenated: out (B,L,H) then energy (B,)

    // workspace: q | bufA | bufB | mu | wt
    float* q    = (float*)d_ws;
    float* bufA = q + BLH;
    float* bufB = bufA + BLH;
    float* mu   = bufB + BLH;
    ushort* Abf = (ushort*)bufA;         // aliases bufA (dead after gemm)
    ushort* wt  = (ushort*)(mu + (size_t)B_ * E);

    int n8 = (int)(BLH / 8);
    conv_bf16_kernel<<<(n8 + 255) / 256, 256, 0, stream>>>(hidden, Abf, n8);
    conv_wqt_kernel<<<dim3(H_ / 64, H_ / 64), 256, 0, stream>>>(wq, wt);
    gemm_q_kernel<<<dim3((B_ * L_) / GBM, H_ / GBN), 256, 0, stream>>>(Abf, wt, bq, q);
    zero_energy_kernel<<<1, 64, 0, stream>>>(energy);

    const int NB = B_ * L_ / 4;          // 8192 blocks, one wave per row
    float coef = 0.1f;                   // ETA * 0.9^step
    const float* st = hidden;
    float* dsts[4] = {bufA, bufB, bufA, bufB};
    for (int s = 0; s < 4; ++s) {
        mu_kernel<<<NB, 256, 0, stream>>>(st, w1, b1, w2, b2, mu);
        float* lno = (s == 3) ? out : nullptr;
        update_kernel<<<NB, 256, 0, stream>>>(st, q, mu, dsts[s],
                                              hidden, gamma, beta, lno, coef);
        st = dsts[s];
        coef *= 0.9f;
    }

    int nchunk = (E + 63) / 64;
    energy_kernel<<<B_ * nchunk, 256, 0, stream>>>(bufB, ei, ej, mu, energy, E);
}